// Round 1
// baseline (314.158 us; speedup 1.0000x reference)
//
#include <hip/hip_runtime.h>
#include <hip/hip_bf16.h>
#include <cstdint>

// ---------------------------------------------------------------------------
// HierDSFeedForward: LN -> shared SwiGLU FFN + hierarchical top-2 MoE
// S=8192 tokens, C=512, H=1024, G=2 groups x EG=4 experts, K=2
// Strategy: bf16 MFMA (16x16x32) GEMMs, m97-style global_load_lds staging.
// ---------------------------------------------------------------------------

typedef __bf16 bf16x8 __attribute__((ext_vector_type(8)));
typedef __bf16 bf16x4 __attribute__((ext_vector_type(4)));
typedef float  f32x4  __attribute__((ext_vector_type(4)));

#define S_TOT 8192
#define C_DIM 512
#define H_DIM 1024

// async global->LDS, 16B per lane. LDS dest must be wave-uniform base; HW
// scatters lane i at base + i*16.
__device__ __forceinline__ void gload_lds16(const void* g, void* l) {
  __builtin_amdgcn_global_load_lds(
      (__attribute__((address_space(1))) void*)(void*)(g),
      (__attribute__((address_space(3))) void*)(l),
      16, 0, 0);
}

// ---------------------------------------------------------------------------
// fp32 -> bf16 (RNE via __bf16 fptrunc), 4 elems/thread
__global__ __launch_bounds__(256) void cvt_f32_bf16(
    const float* __restrict__ src, __bf16* __restrict__ dst, int n) {
  int i = (blockIdx.x * 256 + threadIdx.x) * 4;
  if (i < n) {
    float4 v = *(const float4*)(src + i);
    bf16x4 o;
    o[0] = (__bf16)v.x; o[1] = (__bf16)v.y; o[2] = (__bf16)v.z; o[3] = (__bf16)v.w;
    *(bf16x4*)(dst + i) = o;
  }
}

// ---------------------------------------------------------------------------
// Per-token LayerNorm + hierarchical gating + output bias init.
// One block (256 thr) per token. Gate dot products in fp64 to minimize
// near-tie routing flips vs the numpy reference.
__global__ __launch_bounds__(256) void ln_gate(
    const float* __restrict__ x,
    const float* __restrict__ ln_scale, const float* __restrict__ ln_bias,
    const float* __restrict__ ggw,   // [2,512]
    const float* __restrict__ egw,   // [8,512]
    const float* __restrict__ gb,    // [2]
    const float* __restrict__ eb,    // [8]
    const float* __restrict__ sob,   // [512]
    const float* __restrict__ eob,   // [8,512]
    __bf16* __restrict__ lnb,        // [8192,512] bf16 LN output
    float* __restrict__ comb,        // [8192,8] dense top-2 weights
    float* __restrict__ out)         // [8192,512] init: biases
{
  const int s = blockIdx.x, t = threadIdx.x;
  const int wave = t >> 6, lane = t & 63;
  __shared__ float  sred[4];
  __shared__ double dred[4][10];
  __shared__ float  stats[2];
  __shared__ int    ssel[2];

  const size_t rowb = (size_t)s * C_DIM;
  float v0 = x[rowb + t];
  float v1 = x[rowb + 256 + t];

  // mean
  float sum = v0 + v1;
#pragma unroll
  for (int o = 32; o > 0; o >>= 1) sum += __shfl_down(sum, o, 64);
  if (lane == 0) sred[wave] = sum;
  __syncthreads();
  if (t == 0) stats[0] = (sred[0] + sred[1] + sred[2] + sred[3]) * (1.0f / 512.0f);
  __syncthreads();
  const float mu = stats[0];

  // var
  float d0 = v0 - mu, d1 = v1 - mu;
  float sq = d0 * d0 + d1 * d1;
#pragma unroll
  for (int o = 32; o > 0; o >>= 1) sq += __shfl_down(sq, o, 64);
  if (lane == 0) sred[wave] = sq;
  __syncthreads();
  if (t == 0)
    stats[1] = rsqrtf((sred[0] + sred[1] + sred[2] + sred[3]) * (1.0f / 512.0f) + 1e-5f);
  __syncthreads();
  const float rs = stats[1];

  const float y0 = d0 * rs * ln_scale[t] + ln_bias[t];
  const float y1 = d1 * rs * ln_scale[t + 256] + ln_bias[t + 256];
  lnb[rowb + t]       = (__bf16)y0;
  lnb[rowb + 256 + t] = (__bf16)y1;

  // 10 gate dot products (2 group + 8 expert), fp64 partials
  double p[10];
#pragma unroll
  for (int r = 0; r < 10; r++) {
    const float* W = (r < 2) ? (ggw + r * C_DIM) : (egw + (r - 2) * C_DIM);
    p[r] = (double)y0 * (double)W[t] + (double)y1 * (double)W[t + 256];
  }
#pragma unroll
  for (int o = 32; o > 0; o >>= 1) {
#pragma unroll
    for (int r = 0; r < 10; r++) p[r] += __shfl_down(p[r], o, 64);
  }
  if (lane == 0) {
#pragma unroll
    for (int r = 0; r < 10; r++) dred[wave][r] = p[r];
  }
  __syncthreads();

  if (t == 0) {
    double lg[10];
#pragma unroll
    for (int r = 0; r < 10; r++)
      lg[r] = dred[0][r] + dred[1][r] + dred[2][r] + dred[3][r];
    const double g0 = lg[0] + (double)gb[0], g1 = lg[1] + (double)gb[1];
    const int g = (g1 > g0) ? 1 : 0;  // argmax, first index wins ties
    double el[4], mx = -1e300;
#pragma unroll
    for (int j = 0; j < 4; j++) {
      el[j] = lg[2 + g * 4 + j] + (double)eb[g * 4 + j];
      if (el[j] > mx) mx = el[j];
    }
    double pr[4], ps = 0.0;
#pragma unroll
    for (int j = 0; j < 4; j++) { pr[j] = exp(el[j] - mx); ps += pr[j]; }
    int i0 = 0;
#pragma unroll
    for (int j = 1; j < 4; j++) if (pr[j] > pr[i0]) i0 = j;
    int i1 = -1;
#pragma unroll
    for (int j = 0; j < 4; j++) {
      if (j == i0) continue;
      if (i1 < 0 || pr[j] > pr[i1]) i1 = j;
    }
    const double p0 = pr[i0] / ps, p1 = pr[i1] / ps;
    const double nrm = p0 + p1 + 1e-8;
    const int e0 = g * 4 + i0, e1 = g * 4 + i1;
    ssel[0] = e0; ssel[1] = e1;
    float cw[8] = {0, 0, 0, 0, 0, 0, 0, 0};
    cw[e0] = (float)(p0 / nrm);
    cw[e1] = (float)(p1 / nrm);
#pragma unroll
    for (int j = 0; j < 8; j++) comb[(size_t)s * 8 + j] = cw[j];
  }
  __syncthreads();

  const int e0 = ssel[0], e1 = ssel[1];
  out[rowb + t]       = sob[t]       + eob[e0 * C_DIM + t]       + eob[e1 * C_DIM + t];
  out[rowb + 256 + t] = sob[t + 256] + eob[e0 * C_DIM + t + 256] + eob[e1 * C_DIM + t + 256];
}

// ---------------------------------------------------------------------------
// GEMM1 + fused SwiGLU. A = ln_bf16 [8192,512]; W1 = [4096,512] (rows:
// 0..1023 shared-a, 1024..2047 shared-b, 2048..3071 expert-a, 3072..4095
// expert-b). Block computes 128(M) x 64(N-of-h): accumulates both a and b
// halves in one K-loop, writes silu(a)*b to H [8192,2048] bf16
// (cols 0..1023 = h_shared, 1024..2047 = h_expert).
__global__ __launch_bounds__(256) void gemm1_swiglu(
    const __bf16* __restrict__ A,
    const __bf16* __restrict__ W1,
    __bf16* __restrict__ H)
{
  constexpr int K = C_DIM;  // 512
  __shared__ __bf16 As[128 * 32];
  __shared__ __bf16 Bas[64 * 32];
  __shared__ __bf16 Bbs[64 * 32];

  const int m0 = blockIdx.x * 128;
  const int nh = blockIdx.y * 64;
  const int arow0 = nh + (nh < 1024 ? 0 : 1024);
  const int brow0 = arow0 + 1024;

  const int tid = threadIdx.x, wave = tid >> 6, lane = tid & 63;
  const int wrow = wave >> 1, wcol = wave & 1;
  const int lr16 = lane >> 2;         // staging row-in-16
  const int lc   = (lane & 3) * 8;    // staging col elems
  const int fm   = lane & 15;         // fragment m/n
  const int fq   = (lane >> 4) * 8;   // fragment k base

  f32x4 acca[4][2] = {};
  f32x4 accb[4][2] = {};

  for (int k0 = 0; k0 < K; k0 += 32) {
#pragma unroll
    for (int i = 0; i < 2; i++) {
      const int rb = wave * 2 + i;
      gload_lds16(A + (size_t)(m0 + rb * 16 + lr16) * K + k0 + lc, As + rb * 512);
    }
    gload_lds16(W1 + (size_t)(arow0 + wave * 16 + lr16) * K + k0 + lc, Bas + wave * 512);
    gload_lds16(W1 + (size_t)(brow0 + wave * 16 + lr16) * K + k0 + lc, Bbs + wave * 512);
    __syncthreads();

    bf16x8 af[4], ba[2], bb[2];
#pragma unroll
    for (int mi = 0; mi < 4; mi++)
      af[mi] = *(const bf16x8*)&As[(wrow * 64 + mi * 16 + fm) * 32 + fq];
#pragma unroll
    for (int ni = 0; ni < 2; ni++) {
      const int r = wcol * 32 + ni * 16 + fm;
      ba[ni] = *(const bf16x8*)&Bas[r * 32 + fq];
      bb[ni] = *(const bf16x8*)&Bbs[r * 32 + fq];
    }
#pragma unroll
    for (int mi = 0; mi < 4; mi++) {
#pragma unroll
      for (int ni = 0; ni < 2; ni++) {
        acca[mi][ni] = __builtin_amdgcn_mfma_f32_16x16x32_bf16(af[mi], ba[ni], acca[mi][ni], 0, 0, 0);
        accb[mi][ni] = __builtin_amdgcn_mfma_f32_16x16x32_bf16(af[mi], bb[ni], accb[mi][ni], 0, 0, 0);
      }
    }
    __syncthreads();
  }

  // epilogue: silu(a) * b -> bf16
#pragma unroll
  for (int mi = 0; mi < 4; mi++) {
    const int row0 = m0 + wrow * 64 + mi * 16 + ((lane >> 4) << 2);
#pragma unroll
    for (int ni = 0; ni < 2; ni++) {
      const int c = nh + wcol * 32 + ni * 16 + fm;
#pragma unroll
      for (int r = 0; r < 4; r++) {
        const float a = acca[mi][ni][r];
        const float b = accb[mi][ni][r];
        const float sv = a / (1.0f + __expf(-a));
        H[(size_t)(row0 + r) * (2 * H_DIM) + c] = (__bf16)(sv * b);
      }
    }
  }
}

// ---------------------------------------------------------------------------
// GEMM2: out += scale * (A @ W2[e]^T). z=9: e<8 experts (A = h_expert,
// scale = comb[row,e]), e==8 shared (A = h_shared, scale = 1).
// 128x128 tile, atomicAdd epilogue (rows with scale==0 skipped).
__global__ __launch_bounds__(256) void gemm2(
    const __bf16* __restrict__ Hb,   // [8192, 2048]
    const __bf16* __restrict__ W2,   // [9, 512, 1024]
    const float* __restrict__ comb,  // [8192, 8]
    float* __restrict__ out)         // [8192, 512]
{
  constexpr int K = H_DIM;  // 1024
  __shared__ __bf16 As[128 * 32];
  __shared__ __bf16 Bs[128 * 32];

  const int e = blockIdx.z;
  const int m0 = blockIdx.x * 128, n0 = blockIdx.y * 128;
  const __bf16* Abase = Hb + (e == 8 ? 0 : H_DIM);
  const __bf16* Bw = W2 + (size_t)e * C_DIM * H_DIM;

  const int tid = threadIdx.x, wave = tid >> 6, lane = tid & 63;
  const int wrow = wave >> 1, wcol = wave & 1;
  const int lr16 = lane >> 2;
  const int lc   = (lane & 3) * 8;
  const int fm   = lane & 15;
  const int fq   = (lane >> 4) * 8;

  f32x4 acc[4][4] = {};

  for (int k0 = 0; k0 < K; k0 += 32) {
#pragma unroll
    for (int i = 0; i < 2; i++) {
      const int rb = wave * 2 + i;
      gload_lds16(Abase + (size_t)(m0 + rb * 16 + lr16) * (2 * H_DIM) + k0 + lc, As + rb * 512);
      gload_lds16(Bw + (size_t)(n0 + rb * 16 + lr16) * K + k0 + lc, Bs + rb * 512);
    }
    __syncthreads();

    bf16x8 af[4], bf[4];
#pragma unroll
    for (int mi = 0; mi < 4; mi++)
      af[mi] = *(const bf16x8*)&As[(wrow * 64 + mi * 16 + fm) * 32 + fq];
#pragma unroll
    for (int ni = 0; ni < 4; ni++)
      bf[ni] = *(const bf16x8*)&Bs[(wcol * 64 + ni * 16 + fm) * 32 + fq];
#pragma unroll
    for (int mi = 0; mi < 4; mi++)
#pragma unroll
      for (int ni = 0; ni < 4; ni++)
        acc[mi][ni] = __builtin_amdgcn_mfma_f32_16x16x32_bf16(af[mi], bf[ni], acc[mi][ni], 0, 0, 0);
    __syncthreads();
  }

#pragma unroll
  for (int mi = 0; mi < 4; mi++) {
    const int row0 = m0 + wrow * 64 + mi * 16 + ((lane >> 4) << 2);
#pragma unroll
    for (int r = 0; r < 4; r++) {
      const int row = row0 + r;
      const float scale = (e == 8) ? 1.0f : comb[(size_t)row * 8 + e];
      if (scale != 0.0f) {
#pragma unroll
        for (int ni = 0; ni < 4; ni++) {
          const int c = n0 + wcol * 64 + ni * 16 + fm;
          atomicAdd(&out[(size_t)row * C_DIM + c], scale * acc[mi][ni][r]);
        }
      }
    }
  }
}

// ---------------------------------------------------------------------------
extern "C" void kernel_launch(void* const* d_in, const int* in_sizes, int n_in,
                              void* d_out, int out_size, void* d_ws, size_t ws_size,
                              hipStream_t stream) {
  const float* x    = (const float*)d_in[0];
  const float* lns  = (const float*)d_in[1];
  const float* lnbi = (const float*)d_in[2];
  const float* siw  = (const float*)d_in[3];   // [2048,512]
  const float* sow  = (const float*)d_in[4];   // [512,1024]
  const float* sob  = (const float*)d_in[5];   // [512]
  const float* eiw  = (const float*)d_in[6];   // [2048,512]
  const float* eow  = (const float*)d_in[7];   // [8,512,1024]
  const float* eob  = (const float*)d_in[8];   // [8,512]
  const float* ggw  = (const float*)d_in[9];   // [2,512]
  const float* egw  = (const float*)d_in[10];  // [8,512]
  const float* gb   = (const float*)d_in[11];  // [2]
  const float* eb   = (const float*)d_in[12];  // [8]
  float* out = (float*)d_out;

  // workspace layout (bytes)
  char* ws = (char*)d_ws;
  __bf16* w1   = (__bf16*)(ws);                       //  4,194,304  [4096,512]
  __bf16* w2   = (__bf16*)(ws + 4194304);             //  9,437,184  [9,512,1024]
  __bf16* lnb  = (__bf16*)(ws + 13631488);            //  8,388,608  [8192,512]
  __bf16* Hbuf = (__bf16*)(ws + 22020096);            // 33,554,432  [8192,2048]
  float*  comb = (float*)(ws + 55574528);             //    262,144  [8192,8]
  // total: 55,836,672 bytes

  // 1) weight conversion fp32->bf16
  cvt_f32_bf16<<<1024, 256, 0, stream>>>(siw, w1, 2048 * 512);
  cvt_f32_bf16<<<1024, 256, 0, stream>>>(eiw, w1 + 2048 * 512, 2048 * 512);
  cvt_f32_bf16<<<4096, 256, 0, stream>>>(eow, w2, 8 * 512 * 1024);
  cvt_f32_bf16<<<512, 256, 0, stream>>>(sow, w2 + 8 * 512 * 1024, 512 * 1024);

  // 2) LayerNorm + gating + bias init
  ln_gate<<<S_TOT, 256, 0, stream>>>(x, lns, lnbi, ggw, egw, gb, eb, sob, eob,
                                     lnb, comb, out);

  // 3) GEMM1 + SwiGLU -> H [8192,2048] bf16
  gemm1_swiglu<<<dim3(S_TOT / 128, 2 * H_DIM / 64), 256, 0, stream>>>(lnb, w1, Hbuf);

  // 4) GEMM2 (8 experts + shared) -> atomic accumulate into out
  gemm2<<<dim3(S_TOT / 128, C_DIM / 128, 9), 256, 0, stream>>>(Hbuf, w2, comb, out);
}